// Round 1
// baseline (315.011 us; speedup 1.0000x reference)
//
#include <hip/hip_runtime.h>

// Problem constants
#define BB 16
#define HH 128
#define WW 128
#define CC 256
#define MM (BB*HH*WW)     // 262144
#define KK 512            // 2*CC

typedef __attribute__((ext_vector_type(8))) short s16x8;
typedef __attribute__((ext_vector_type(4))) float f32x4;

__device__ static inline unsigned short f2bf(float x) {
    union { float f; unsigned u; } v; v.f = x;
    unsigned r = v.u + 0x7fffu + ((v.u >> 16) & 1u);  // round-nearest-even
    return (unsigned short)(r >> 16);
}

__device__ static inline void gload_lds16(const void* g, void* l) {
    __builtin_amdgcn_global_load_lds(
        (const __attribute__((address_space(1))) void*)g,
        (__attribute__((address_space(3))) void*)l,
        16, 0, 0);
}

// ---- Pass 1a: cummax along w. One thread per (b,h,c4); lanes span c -> coalesced.
__global__ __launch_bounds__(256) void scan_w_kernel(const float* __restrict__ grid,
                                                     unsigned short* __restrict__ A) {
    const int t  = threadIdx.x;
    const int bh = blockIdx.x * 4 + (t >> 6);   // 0..2047
    const int c4 = t & 63;                       // float4 index, c = 4*c4
    const float4* src = (const float4*)(grid + (size_t)bh * WW * CC) + c4;
    unsigned short* dst = A + (size_t)bh * WW * KK + c4 * 4;  // + w*KK
    float4 run = make_float4(-3.4e38f, -3.4e38f, -3.4e38f, -3.4e38f);
    #pragma unroll 4
    for (int w = 0; w < WW; ++w) {
        float4 v = src[(size_t)w * (CC/4)];
        run.x = fmaxf(run.x, v.x); run.y = fmaxf(run.y, v.y);
        run.z = fmaxf(run.z, v.z); run.w = fmaxf(run.w, v.w);
        ushort4 o;
        o.x = f2bf(run.x); o.y = f2bf(run.y); o.z = f2bf(run.z); o.w = f2bf(run.w);
        *(ushort4*)(dst + (size_t)w * KK) = o;
    }
}

// ---- Pass 1b: cummax along h. One thread per (b,w,c4).
__global__ __launch_bounds__(256) void scan_h_kernel(const float* __restrict__ grid,
                                                     unsigned short* __restrict__ A) {
    const int t  = threadIdx.x;
    const int bw = blockIdx.x * 4 + (t >> 6);   // 0..2047
    const int b  = bw >> 7;
    const int w  = bw & 127;
    const int c4 = t & 63;
    const float4* src = (const float4*)(grid + ((size_t)b * HH * WW + w) * CC) + c4;
    unsigned short* dst = A + ((size_t)b * HH * WW + w) * KK + CC + c4 * 4;
    float4 run = make_float4(-3.4e38f, -3.4e38f, -3.4e38f, -3.4e38f);
    #pragma unroll 4
    for (int h = 0; h < HH; ++h) {
        float4 v = src[(size_t)h * (WW * CC / 4)];
        run.x = fmaxf(run.x, v.x); run.y = fmaxf(run.y, v.y);
        run.z = fmaxf(run.z, v.z); run.w = fmaxf(run.w, v.w);
        ushort4 o;
        o.x = f2bf(run.x); o.y = f2bf(run.y); o.z = f2bf(run.z); o.w = f2bf(run.w);
        *(ushort4*)(dst + (size_t)h * WW * KK) = o;
    }
}

// ---- Pass 2: W[512,256] f32 -> Wt bf16 k-grouped: Wt[(k/8)*256 + n][k%8]
__global__ __launch_bounds__(256) void conv_w_kernel(const float* __restrict__ Wf,
                                                     unsigned short* __restrict__ Wt) {
    const int i = blockIdx.x * 256 + threadIdx.x;   // 0..131071
    const int k = i >> 8, n = i & 255;
    Wt[(((size_t)(k >> 3) * 256 + n) << 3) + (k & 7)] = f2bf(Wf[i]);
}

// ---- Pass 3: out[M,256] = A[M,512](bf16) @ W(bf16) + bias, f32 out.
// BM=128, BN=256 (full N), BK=64. 512 threads = 8 waves (2 x 4), each wave 64x64.
__global__ __launch_bounds__(512) void gemm_kernel(const unsigned short* __restrict__ A,
                                                   const unsigned short* __restrict__ Wt,
                                                   const float* __restrict__ bias,
                                                   float* __restrict__ out) {
    // LDS: A tile [128 rows][8 chunks of 16B] (XOR-swizzled), B tile [8 g][256 n][8 k] bf16
    __shared__ __align__(16) unsigned char lds[49152];
    unsigned char* Al = lds;            // 16 KB
    unsigned char* Bl = lds + 16384;    // 32 KB

    const int t    = threadIdx.x;
    const int lane = t & 63;
    const int wid  = t >> 6;
    const int wm   = wid >> 2;          // 0..1
    const int wn   = wid & 3;           // 0..3
    const size_t m0 = (size_t)blockIdx.x * 128;

    const f32x4 fzero = {0.f, 0.f, 0.f, 0.f};
    f32x4 acc[4][4];
    #pragma unroll
    for (int i = 0; i < 4; ++i)
        #pragma unroll
        for (int j = 0; j < 4; ++j) acc[i][j] = fzero;

    const unsigned short* Arow = A + m0 * KK;

    for (int k0 = 0; k0 < KK; k0 += 64) {
        // stage A tile: 128 rows x 64 k (16 KB), inverse-swizzled source -> linear LDS dest
        #pragma unroll
        for (int i = 0; i < 2; ++i) {
            const int tt  = t + i * 512;        // 0..1023
            const int row = tt >> 3;
            const int ch  = tt & 7;
            const int sc  = ch ^ (row & 7);     // logical chunk this phys slot holds
            gload_lds16(Arow + (size_t)row * KK + k0 + sc * 8, Al + tt * 16);
        }
        // stage B tile: contiguous 32 KB of k-grouped Wt
        const unsigned short* Bsrc = Wt + (size_t)k0 * 256;
        #pragma unroll
        for (int i = 0; i < 4; ++i) {
            const int idx = t + i * 512;        // 0..2047
            gload_lds16(Bsrc + (size_t)idx * 8, Bl + idx * 16);
        }
        __syncthreads();   // drains vmcnt -> tiles ready

        #pragma unroll
        for (int kk = 0; kk < 2; ++kk) {
            s16x8 af[4], bfr[4];
            const int g = 4 * kk + (lane >> 4);       // 16B-chunk index within BK
            #pragma unroll
            for (int fm = 0; fm < 4; ++fm) {
                const int row = wm * 64 + fm * 16 + (lane & 15);
                const int pc  = g ^ (row & 7);
                af[fm] = *(const s16x8*)(Al + row * 128 + pc * 16);
            }
            #pragma unroll
            for (int fn = 0; fn < 4; ++fn) {
                const int n = wn * 64 + fn * 16 + (lane & 15);
                bfr[fn] = *(const s16x8*)(Bl + ((size_t)g * 256 + n) * 16);
            }
            #pragma unroll
            for (int fm = 0; fm < 4; ++fm)
                #pragma unroll
                for (int fn = 0; fn < 4; ++fn)
                    acc[fm][fn] = __builtin_amdgcn_mfma_f32_16x16x32_bf16(
                        af[fm], bfr[fn], acc[fm][fn], 0, 0, 0);
        }
        __syncthreads();   // tiles consumed before next overwrite
    }

    // epilogue: C/D layout col = lane&15, row = (lane>>4)*4 + reg   [m89/m91]
    #pragma unroll
    for (int fn = 0; fn < 4; ++fn) {
        const int col = wn * 64 + fn * 16 + (lane & 15);
        const float bb = bias[col];
        #pragma unroll
        for (int fm = 0; fm < 4; ++fm) {
            const int rbase = wm * 64 + fm * 16 + ((lane >> 4) << 2);
            #pragma unroll
            for (int r = 0; r < 4; ++r) {
                out[(m0 + rbase + r) * (size_t)CC + col] = acc[fm][fn][r] + bb;
            }
        }
    }
}

extern "C" void kernel_launch(void* const* d_in, const int* in_sizes, int n_in,
                              void* d_out, int out_size, void* d_ws, size_t ws_size,
                              hipStream_t stream) {
    const float* grid = (const float*)d_in[0];
    const float* Wf   = (const float*)d_in[1];
    const float* bias = (const float*)d_in[2];
    float* out        = (float*)d_out;

    // workspace: A bf16 [M,512] = 256 MB, then Wt bf16 [512*256] = 256 KB
    unsigned short* A  = (unsigned short*)d_ws;
    unsigned short* Wt = (unsigned short*)((char*)d_ws + (size_t)MM * KK * 2);

    conv_w_kernel<<<512, 256, 0, stream>>>(Wf, Wt);
    scan_w_kernel<<<512, 256, 0, stream>>>(grid, A);
    scan_h_kernel<<<512, 256, 0, stream>>>(grid, A);
    gemm_kernel<<<2048, 512, 0, stream>>>(A, Wt, bias, out);
}

// Round 2
// 303.416 us; speedup vs baseline: 1.0382x; 1.0382x over previous
//
#include <hip/hip_runtime.h>

// Problem constants
#define BB 16
#define HH 128
#define WW 128
#define CC 256
#define MM (BB*HH*WW)     // 262144
#define KK 512            // 2*CC
#define NT 8              // K-tiles of BK=64

typedef __attribute__((ext_vector_type(8))) short s16x8;
typedef __attribute__((ext_vector_type(4))) float f32x4;

__device__ static inline unsigned short f2bf(float x) {
    union { float f; unsigned u; } v; v.f = x;
    unsigned r = v.u + 0x7fffu + ((v.u >> 16) & 1u);  // round-nearest-even
    return (unsigned short)(r >> 16);
}

__device__ static inline void gload_lds16(const void* g, void* l) {
    __builtin_amdgcn_global_load_lds(
        (const __attribute__((address_space(1))) void*)g,
        (__attribute__((address_space(3))) void*)l,
        16, 0, 0);
}

// ---- Fused prep: blocks [0,512) w-scan, [512,1024) h-scan, [1024,1088) W conv.
__global__ __launch_bounds__(256) void prep_kernel(const float* __restrict__ grid,
                                                   const float* __restrict__ Wf,
                                                   unsigned short* __restrict__ A,
                                                   unsigned short* __restrict__ Wt) {
    const int bid = blockIdx.x;
    const int t   = threadIdx.x;
    if (bid < 512) {
        // cummax along w; one thread per (b,h,c4), lanes span c -> coalesced
        const int bh = bid * 4 + (t >> 6);
        const int c4 = t & 63;
        const float4* src = (const float4*)(grid + (size_t)bh * WW * CC) + c4;
        unsigned short* dst = A + (size_t)bh * WW * KK + c4 * 4;
        float4 run = make_float4(-3.4e38f, -3.4e38f, -3.4e38f, -3.4e38f);
        #pragma unroll 8
        for (int w = 0; w < WW; ++w) {
            float4 v = src[(size_t)w * (CC/4)];
            run.x = fmaxf(run.x, v.x); run.y = fmaxf(run.y, v.y);
            run.z = fmaxf(run.z, v.z); run.w = fmaxf(run.w, v.w);
            ushort4 o;
            o.x = f2bf(run.x); o.y = f2bf(run.y); o.z = f2bf(run.z); o.w = f2bf(run.w);
            *(ushort4*)(dst + (size_t)w * KK) = o;
        }
    } else if (bid < 1024) {
        // cummax along h; one thread per (b,w,c4)
        const int bw = (bid - 512) * 4 + (t >> 6);
        const int b  = bw >> 7;
        const int w  = bw & 127;
        const int c4 = t & 63;
        const float4* src = (const float4*)(grid + ((size_t)b * HH * WW + w) * CC) + c4;
        unsigned short* dst = A + ((size_t)b * HH * WW + w) * KK + CC + c4 * 4;
        float4 run = make_float4(-3.4e38f, -3.4e38f, -3.4e38f, -3.4e38f);
        #pragma unroll 8
        for (int h = 0; h < HH; ++h) {
            float4 v = src[(size_t)h * (WW * CC / 4)];
            run.x = fmaxf(run.x, v.x); run.y = fmaxf(run.y, v.y);
            run.z = fmaxf(run.z, v.z); run.w = fmaxf(run.w, v.w);
            ushort4 o;
            o.x = f2bf(run.x); o.y = f2bf(run.y); o.z = f2bf(run.z); o.w = f2bf(run.w);
            *(ushort4*)(dst + (size_t)h * WW * KK) = o;
        }
    } else {
        // W[512,256] f32 -> Wt bf16 k-grouped: Wt[(k/8)*256 + n][k%8]
        const int base = (bid - 1024) * 2048;
        #pragma unroll 8
        for (int j = 0; j < 8; ++j) {
            const int i = base + j * 256 + t;   // 0..131071
            const int k = i >> 8, n = i & 255;
            Wt[(((size_t)(k >> 3) * 256 + n) << 3) + (k & 7)] = f2bf(Wf[i]);
        }
    }
}

// ---- GEMM: out[M,256] = A[M,512](bf16) @ W(bf16) + bias, f32 out.
// BM=256, BN=128, BK=64. 512 threads = 8 waves (4 wm x 2 wn), wave = 64x64.
// Ring-of-3 LDS tile buffers (48 KB each = A 32K + B 16K), 2 phases/K-tile,
// counted vmcnt(6) gate once per K-tile (T3+T4), setprio around MFMA (T5).
__global__ __launch_bounds__(512, 2) void gemm_kernel(const unsigned short* __restrict__ Ag,
                                                      const unsigned short* __restrict__ Wt,
                                                      const float* __restrict__ bias,
                                                      float* __restrict__ out) {
    __shared__ __align__(16) unsigned char lds[147456];   // 3 x 49152

    const int t    = threadIdx.x;
    const int lane = t & 63;
    const int wid  = t >> 6;
    const int wm   = wid >> 1;          // 0..3 -> rows wm*64..+63
    const int wn   = wid & 1;           // 0..1 -> cols wn*64..+63 (of 128)
    const int bid  = blockIdx.x;
    const size_t m0 = (size_t)(bid >> 1) * 256;
    const int n0    = (bid & 1) * 128;

    const f32x4 fzero = {0.f, 0.f, 0.f, 0.f};
    f32x4 acc[4][4];
    #pragma unroll
    for (int i = 0; i < 4; ++i)
        #pragma unroll
        for (int j = 0; j < 4; ++j) acc[i][j] = fzero;

    // fragment LDS byte offsets (kk=0); kk=1: A ^64, B +8192
    int aoff[4], boff[4];
    #pragma unroll
    for (int fm = 0; fm < 4; ++fm) {
        const int row = wm * 64 + fm * 16 + (lane & 15);
        const int pc  = (lane >> 4) ^ (row & 7);
        aoff[fm] = row * 128 + pc * 16;
    }
    #pragma unroll
    for (int fn = 0; fn < 4; ++fn) {
        const int n = wn * 64 + fn * 16 + (lane & 15);
        boff[fn] = (lane >> 4) * 2048 + n * 16;
    }

    // staging (per thread): A 4 x 16B, B 2 x 16B per K-tile
    auto stageA = [&](int tt, int i, unsigned char* dstA) {
        const int f   = t + i * 512;        // 0..2047
        const int row = f >> 3;
        const int sc  = (f & 7) ^ (row & 7);
        gload_lds16(Ag + (m0 + row) * (size_t)KK + tt * 64 + sc * 8, dstA + f * 16);
    };
    auto stageB = [&](int tt, int i, unsigned char* dstB) {
        const int f = t + i * 512;          // 0..1023
        const int g = f >> 7, n = f & 127;
        gload_lds16(Wt + ((size_t)(tt * 8 + g) * 256 + n0 + n) * 8, dstB + f * 16);
    };

    // prologue: issue tiles 0 and 1 (6 loads each, in tile order)
    {
        unsigned char* A0 = lds;              unsigned char* B0 = lds + 32768;
        unsigned char* A1 = lds + 49152;      unsigned char* B1 = lds + 49152 + 32768;
        stageA(0,0,A0); stageA(0,1,A0); stageA(0,2,A0); stageA(0,3,A0);
        stageB(0,0,B0); stageB(0,1,B0);
        stageA(1,0,A1); stageA(1,1,A1); stageA(1,2,A1); stageA(1,3,A1);
        stageB(1,0,B1); stageB(1,1,B1);
    }
    asm volatile("s_waitcnt vmcnt(6)" ::: "memory");   // tile0 landed (tile1 in flight)
    __builtin_amdgcn_s_barrier();

    int cur = 0;
    for (int tt = 0; tt < NT; ++tt) {
        int b2 = cur + 2; if (b2 >= 3) b2 -= 3;
        const unsigned char* Ac = lds + cur * 49152;
        const unsigned char* Bc = Ac + 32768;
        unsigned char* As = lds + b2 * 49152;
        unsigned char* Bs = As + 32768;
        const bool issue = (tt + 2 < NT);

        #pragma unroll
        for (int q = 0; q < 2; ++q) {          // kk halves of BK=64
            s16x8 af[4], bfr[4];
            const int ax = q * 64, bx = q * 8192;
            #pragma unroll
            for (int fm = 0; fm < 4; ++fm) af[fm] = *(const s16x8*)(Ac + (aoff[fm] ^ ax));
            #pragma unroll
            for (int fn = 0; fn < 4; ++fn) bfr[fn] = *(const s16x8*)(Bc + boff[fn] + bx);

            if (issue) {                        // 3 gloads/phase, tile tt+2
                stageA(tt + 2, 2 * q,     As);
                stageA(tt + 2, 2 * q + 1, As);
                stageB(tt + 2, q,         Bs);
            }
            __builtin_amdgcn_s_barrier();
            asm volatile("s_waitcnt lgkmcnt(0)" ::: "memory");
            __builtin_amdgcn_sched_barrier(0);
            __builtin_amdgcn_s_setprio(1);
            #pragma unroll
            for (int fm = 0; fm < 4; ++fm)
                #pragma unroll
                for (int fn = 0; fn < 4; ++fn)
                    acc[fm][fn] = __builtin_amdgcn_mfma_f32_16x16x32_bf16(
                        af[fm], bfr[fn], acc[fm][fn], 0, 0, 0);
            __builtin_amdgcn_s_setprio(0);
            if (q == 1) {                       // gate tile tt+1, once per K-tile
                if (tt < NT - 2) {
                    asm volatile("s_waitcnt vmcnt(6)" ::: "memory");
                } else if (tt == NT - 2) {
                    asm volatile("s_waitcnt vmcnt(0)" ::: "memory");
                }
            }
            __builtin_amdgcn_s_barrier();
        }
        cur = cur + 1 == 3 ? 0 : cur + 1;
    }

    // epilogue: C/D layout col = lane&15, row = (lane>>4)*4 + reg   [verified r0]
    #pragma unroll
    for (int fn = 0; fn < 4; ++fn) {
        const int col = n0 + wn * 64 + fn * 16 + (lane & 15);
        const float bb = bias[col];
        #pragma unroll
        for (int fm = 0; fm < 4; ++fm) {
            const int rbase = wm * 64 + fm * 16 + ((lane >> 4) << 2);
            #pragma unroll
            for (int r = 0; r < 4; ++r) {
                out[(m0 + rbase + r) * (size_t)CC + col] = acc[fm][fn][r] + bb;
            }
        }
    }
}

extern "C" void kernel_launch(void* const* d_in, const int* in_sizes, int n_in,
                              void* d_out, int out_size, void* d_ws, size_t ws_size,
                              hipStream_t stream) {
    const float* grid = (const float*)d_in[0];
    const float* Wf   = (const float*)d_in[1];
    const float* bias = (const float*)d_in[2];
    float* out        = (float*)d_out;

    // workspace: A bf16 [M,512] = 256 MB, then Wt bf16 [512*256] = 256 KB
    unsigned short* A  = (unsigned short*)d_ws;
    unsigned short* Wt = (unsigned short*)((char*)d_ws + (size_t)MM * KK * 2);

    prep_kernel<<<1088, 256, 0, stream>>>(grid, Wf, A, Wt);
    gemm_kernel<<<2048, 512, 0, stream>>>(A, Wt, bias, out);
}

// Round 3
// 295.450 us; speedup vs baseline: 1.0662x; 1.0270x over previous
//
#include <hip/hip_runtime.h>

// Problem constants
#define BB 16
#define HH 128
#define WW 128
#define CC 256
#define MM (BB*HH*WW)     // 262144
#define KK 512            // 2*CC
#define NT 8              // K-tiles of BK=64

typedef __attribute__((ext_vector_type(8))) short s16x8;
typedef __attribute__((ext_vector_type(4))) float f32x4;

__device__ static inline unsigned short f2bf(float x) {
    union { float f; unsigned u; } v; v.f = x;
    unsigned r = v.u + 0x7fffu + ((v.u >> 16) & 1u);  // round-nearest-even
    return (unsigned short)(r >> 16);
}

__device__ static inline void gload_lds16(const void* g, void* l) {
    __builtin_amdgcn_global_load_lds(
        (const __attribute__((address_space(1))) void*)g,
        (__attribute__((address_space(3))) void*)l,
        16, 0, 0);
}

// ---- Fused prep, single-wave blocks for even distribution + explicit MLP=8.
// blocks [0,2048): w-scan, one (b,h) row per wave
// blocks [2048,4096): h-scan, one (b,w) column per wave
// blocks [4096,4160): W f32 -> bf16 k-grouped conversion
__global__ __launch_bounds__(64) void prep_kernel(const float* __restrict__ grid,
                                                  const float* __restrict__ Wf,
                                                  unsigned short* __restrict__ A,
                                                  unsigned short* __restrict__ Wt) {
    const int bid = blockIdx.x;
    const int t   = threadIdx.x;   // 0..63, c4 = t (4 channels per lane)

    if (bid < 4096) {
        const bool is_w = (bid < 2048);
        const float4* src;
        unsigned short* dst;
        size_t sstride, dstride;   // in float4 / ushort units per scan step
        if (is_w) {
            const int bh = bid;
            src = (const float4*)(grid + (size_t)bh * WW * CC) + t;
            dst = A + (size_t)bh * WW * KK + t * 4;
            sstride = CC / 4;          // next w
            dstride = KK;
        } else {
            const int bw = bid - 2048;
            const int b = bw >> 7, w = bw & 127;
            src = (const float4*)(grid + ((size_t)b * HH * WW + w) * CC) + t;
            dst = A + ((size_t)b * HH * WW + w) * KK + CC + t * 4;
            sstride = (size_t)WW * CC / 4;   // next h
            dstride = (size_t)WW * KK;
        }
        float4 buf[8];
        #pragma unroll
        for (int j = 0; j < 8; ++j) buf[j] = src[(size_t)j * sstride];
        float4 run = make_float4(-3.4e38f, -3.4e38f, -3.4e38f, -3.4e38f);
        for (int w = 0; w < 128; w += 8) {
            float4 nbuf[8];
            const bool more = (w + 8 < 128);
            if (more) {
                #pragma unroll
                for (int j = 0; j < 8; ++j) nbuf[j] = src[(size_t)(w + 8 + j) * sstride];
            }
            #pragma unroll
            for (int j = 0; j < 8; ++j) {
                float4 v = buf[j];
                run.x = fmaxf(run.x, v.x); run.y = fmaxf(run.y, v.y);
                run.z = fmaxf(run.z, v.z); run.w = fmaxf(run.w, v.w);
                ushort4 o;
                o.x = f2bf(run.x); o.y = f2bf(run.y);
                o.z = f2bf(run.z); o.w = f2bf(run.w);
                *(ushort4*)(dst + (size_t)(w + j) * dstride) = o;
            }
            if (more) {
                #pragma unroll
                for (int j = 0; j < 8; ++j) buf[j] = nbuf[j];
            }
        }
    } else {
        // W[512,256] f32 -> Wt bf16 k-grouped: Wt[(k/8)*256 + n][k%8]
        const int base = (bid - 4096) * 2048;
        #pragma unroll 8
        for (int j = 0; j < 32; ++j) {
            const int i = base + j * 64 + t;   // 0..131071
            const int k = i >> 8, n = i & 255;
            Wt[(((size_t)(k >> 3) * 256 + n) << 3) + (k & 7)] = f2bf(Wf[i]);
        }
    }
}

// ---- GEMM: out[M,256] = A[M,512](bf16) @ W(bf16) + bias, f32 out.
// BM=256, BN=128, BK=64. 512 threads = 8 waves (4 wm x 2 wn), wave = 64x64.
// Ring-of-3 LDS tile buffers (48 KB each = A 32K + B 16K), 2 phases/K-tile,
// counted vmcnt(6) gate once per K-tile (T3+T4), setprio around MFMA (T5).
__global__ __launch_bounds__(512, 2) void gemm_kernel(const unsigned short* __restrict__ Ag,
                                                      const unsigned short* __restrict__ Wt,
                                                      const float* __restrict__ bias,
                                                      float* __restrict__ out) {
    __shared__ __align__(16) unsigned char lds[147456];   // 3 x 49152

    const int t    = threadIdx.x;
    const int lane = t & 63;
    const int wid  = t >> 6;
    const int wm   = wid >> 1;          // 0..3 -> rows wm*64..+63
    const int wn   = wid & 1;           // 0..1 -> cols wn*64..+63 (of 128)
    const int bid  = blockIdx.x;
    const size_t m0 = (size_t)(bid >> 1) * 256;
    const int n0    = (bid & 1) * 128;

    const f32x4 fzero = {0.f, 0.f, 0.f, 0.f};
    f32x4 acc[4][4];
    #pragma unroll
    for (int i = 0; i < 4; ++i)
        #pragma unroll
        for (int j = 0; j < 4; ++j) acc[i][j] = fzero;

    // fragment LDS byte offsets (kk=0); kk=1: A ^64, B +8192
    int aoff[4], boff[4];
    #pragma unroll
    for (int fm = 0; fm < 4; ++fm) {
        const int row = wm * 64 + fm * 16 + (lane & 15);
        const int pc  = (lane >> 4) ^ (row & 7);
        aoff[fm] = row * 128 + pc * 16;
    }
    #pragma unroll
    for (int fn = 0; fn < 4; ++fn) {
        const int n = wn * 64 + fn * 16 + (lane & 15);
        boff[fn] = (lane >> 4) * 2048 + n * 16;
    }

    // staging (per thread): A 4 x 16B, B 2 x 16B per K-tile
    auto stageA = [&](int tt, int i, unsigned char* dstA) {
        const int f   = t + i * 512;        // 0..2047
        const int row = f >> 3;
        const int sc  = (f & 7) ^ (row & 7);
        gload_lds16(Ag + (m0 + row) * (size_t)KK + tt * 64 + sc * 8, dstA + f * 16);
    };
    auto stageB = [&](int tt, int i, unsigned char* dstB) {
        const int f = t + i * 512;          // 0..1023
        const int g = f >> 7, n = f & 127;
        gload_lds16(Wt + ((size_t)(tt * 8 + g) * 256 + n0 + n) * 8, dstB + f * 16);
    };

    // prologue: issue tiles 0 and 1 (6 loads each, in tile order)
    {
        unsigned char* A0 = lds;              unsigned char* B0 = lds + 32768;
        unsigned char* A1 = lds + 49152;      unsigned char* B1 = lds + 49152 + 32768;
        stageA(0,0,A0); stageA(0,1,A0); stageA(0,2,A0); stageA(0,3,A0);
        stageB(0,0,B0); stageB(0,1,B0);
        stageA(1,0,A1); stageA(1,1,A1); stageA(1,2,A1); stageA(1,3,A1);
        stageB(1,0,B1); stageB(1,1,B1);
    }
    asm volatile("s_waitcnt vmcnt(6)" ::: "memory");   // tile0 landed (tile1 in flight)
    __builtin_amdgcn_s_barrier();

    int cur = 0;
    for (int tt = 0; tt < NT; ++tt) {
        int b2 = cur + 2; if (b2 >= 3) b2 -= 3;
        const unsigned char* Ac = lds + cur * 49152;
        const unsigned char* Bc = Ac + 32768;
        unsigned char* As = lds + b2 * 49152;
        unsigned char* Bs = As + 32768;
        const bool issue = (tt + 2 < NT);

        #pragma unroll
        for (int q = 0; q < 2; ++q) {          // kk halves of BK=64
            s16x8 af[4], bfr[4];
            const int ax = q * 64, bx = q * 8192;
            #pragma unroll
            for (int fm = 0; fm < 4; ++fm) af[fm] = *(const s16x8*)(Ac + (aoff[fm] ^ ax));
            #pragma unroll
            for (int fn = 0; fn < 4; ++fn) bfr[fn] = *(const s16x8*)(Bc + boff[fn] + bx);

            if (issue) {                        // 3 gloads/phase, tile tt+2
                stageA(tt + 2, 2 * q,     As);
                stageA(tt + 2, 2 * q + 1, As);
                stageB(tt + 2, q,         Bs);
            }
            __builtin_amdgcn_s_barrier();
            asm volatile("s_waitcnt lgkmcnt(0)" ::: "memory");
            __builtin_amdgcn_sched_barrier(0);
            __builtin_amdgcn_s_setprio(1);
            #pragma unroll
            for (int fm = 0; fm < 4; ++fm)
                #pragma unroll
                for (int fn = 0; fn < 4; ++fn)
                    acc[fm][fn] = __builtin_amdgcn_mfma_f32_16x16x32_bf16(
                        af[fm], bfr[fn], acc[fm][fn], 0, 0, 0);
            __builtin_amdgcn_s_setprio(0);
            if (q == 1) {                       // gate tile tt+1, once per K-tile
                if (tt < NT - 2) {
                    asm volatile("s_waitcnt vmcnt(6)" ::: "memory");
                } else if (tt == NT - 2) {
                    asm volatile("s_waitcnt vmcnt(0)" ::: "memory");
                }
            }
            __builtin_amdgcn_s_barrier();
        }
        cur = cur + 1 == 3 ? 0 : cur + 1;
    }

    // epilogue: C/D layout col = lane&15, row = (lane>>4)*4 + reg   [verified r0]
    #pragma unroll
    for (int fn = 0; fn < 4; ++fn) {
        const int col = n0 + wn * 64 + fn * 16 + (lane & 15);
        const float bb = bias[col];
        #pragma unroll
        for (int fm = 0; fm < 4; ++fm) {
            const int rbase = wm * 64 + fm * 16 + ((lane >> 4) << 2);
            #pragma unroll
            for (int r = 0; r < 4; ++r) {
                out[(m0 + rbase + r) * (size_t)CC + col] = acc[fm][fn][r] + bb;
            }
        }
    }
}

extern "C" void kernel_launch(void* const* d_in, const int* in_sizes, int n_in,
                              void* d_out, int out_size, void* d_ws, size_t ws_size,
                              hipStream_t stream) {
    const float* grid = (const float*)d_in[0];
    const float* Wf   = (const float*)d_in[1];
    const float* bias = (const float*)d_in[2];
    float* out        = (float*)d_out;

    // workspace: A bf16 [M,512] = 256 MB, then Wt bf16 [512*256] = 256 KB
    unsigned short* A  = (unsigned short*)d_ws;
    unsigned short* Wt = (unsigned short*)((char*)d_ws + (size_t)MM * KK * 2);

    prep_kernel<<<4160, 64, 0, stream>>>(grid, Wf, A, Wt);
    gemm_kernel<<<2048, 512, 0, stream>>>(A, Wt, bias, out);
}